// Round 2
// baseline (1674.090 us; speedup 1.0000x reference)
//
#include <hip/hip_runtime.h>
#include <hip/hip_bf16.h>

#define Hn 512
#define Wn 512
#define HWn (512 * 512)
#define KTOP 26214

__device__ __forceinline__ float sigf(float z) { return 1.0f / (1.0f + __expf(-z)); }

// ---- kernel 1: per (b,c) sums of x (for color) ----
__global__ __launch_bounds__(256) void k_means(const float* __restrict__ x, float* __restrict__ means) {
  int bc = blockIdx.x >> 5;     // 0..23
  int slice = blockIdx.x & 31;  // 0..31
  const float* p = x + bc * HWn + slice * 8192;
  float s = 0.f;
  for (int i = threadIdx.x; i < 8192; i += 256) s += p[i];
  for (int off = 32; off > 0; off >>= 1) s += __shfl_down(s, off);
  if ((threadIdx.x & 63) == 0) atomicAdd(&means[bc], s);
}

// ---- kernel 2: fused conv1+relu+conv2+sigmoid+color+1x1conv+x_out ----
__global__ __launch_bounds__(256) void k_fused(
    const float* __restrict__ x, const float* __restrict__ w1, const float* __restrict__ b1,
    const float* __restrict__ w2, const float* __restrict__ b2,
    const float* __restrict__ cw, const float* __restrict__ cb,
    const float* __restrict__ convw, const float* __restrict__ convb,
    const float* __restrict__ means, float* __restrict__ out)
{
  __shared__ float xs[3][20][20];   // x tile with halo 2
  __shared__ float hs[16][18][18];  // h chunk with halo 1
  __shared__ float w1s[64 * 27];
  __shared__ float w2s[64 * 27];    // layout [ic][tap][oc]
  __shared__ float b1s[64];
  __shared__ float b2s[3];
  __shared__ float colorS[3];
  __shared__ float cwS[12];
  __shared__ float cbS[4];

  const int tid = threadIdx.x;
  const int tx0 = blockIdx.x * 16;
  const int ty0 = blockIdx.y * 16;
  const int b   = blockIdx.z;

  for (int i = tid; i < 64 * 27; i += 256) w1s[i] = w1[i];
  for (int i = tid; i < 64 * 27; i += 256) {
    int ic = i / 27, r = i % 27, tap = r / 3, oc = r % 3;
    w2s[i] = w2[oc * 576 + ic * 9 + tap];
  }
  if (tid < 64) b1s[tid] = b1[tid];
  if (tid < 3)  b2s[tid] = b2[tid];
  if (tid < 12) cwS[tid] = convw[tid];
  if (tid < 4)  cbS[tid] = convb[tid];
  if (tid < 3) {
    float z = cb[tid];
    for (int j = 0; j < 3; ++j)
      z += (means[b * 3 + j] * (1.0f / (float)HWn)) * cw[tid * 3 + j];
    colorS[tid] = sigf(z);
  }
  for (int i = tid; i < 1200; i += 256) {
    int c = i / 400, r = i % 400, yy = r / 20, xx = r % 20;
    int gy = ty0 - 2 + yy, gx = tx0 - 2 + xx;
    float v = 0.f;
    if ((unsigned)gy < (unsigned)Hn && (unsigned)gx < (unsigned)Wn)
      v = x[(b * 3 + c) * HWn + (gy << 9) + gx];
    xs[c][yy][xx] = v;
  }
  __syncthreads();

  const int px = tid & 15, py = tid >> 4;   // conv2 output pixel
  const int cl = tid & 15, pg = tid >> 4;   // conv1 channel / pixel-group
  float a0 = 0.f, a1 = 0.f, a2 = 0.f;

  for (int cc = 0; cc < 4; ++cc) {
    const int hc = cc * 16 + cl;
    float wr[27];
#pragma unroll
    for (int t = 0; t < 27; ++t) wr[t] = w1s[hc * 27 + t];
    const float bias = b1s[hc];
    for (int p = pg; p < 324; p += 16) {
      int hy = p / 18, hx = p - hy * 18;
      int gy = ty0 - 1 + hy, gx = tx0 - 1 + hx;
      float h = 0.f;
      if ((unsigned)gy < (unsigned)Hn && (unsigned)gx < (unsigned)Wn) {
        h = bias;
#pragma unroll
        for (int ic = 0; ic < 3; ++ic)
#pragma unroll
          for (int ky = 0; ky < 3; ++ky)
#pragma unroll
            for (int kx = 0; kx < 3; ++kx)
              h += xs[ic][hy + ky][hx + kx] * wr[ic * 9 + ky * 3 + kx];
        h = fmaxf(h, 0.f);  // out-of-image h stays 0 (conv2 zero-pad)
      }
      hs[cl][hy][hx] = h;
    }
    __syncthreads();
#pragma unroll 4
    for (int c = 0; c < 16; ++c) {
      const int base = (cc * 16 + c) * 27;
#pragma unroll
      for (int ky = 0; ky < 3; ++ky)
#pragma unroll
        for (int kx = 0; kx < 3; ++kx) {
          float hv = hs[c][py + ky][px + kx];
          int wi = base + (ky * 3 + kx) * 3;
          a0 += hv * w2s[wi];
          a1 += hv * w2s[wi + 1];
          a2 += hv * w2s[wi + 2];
        }
    }
    __syncthreads();
  }

  float ih0 = colorS[0] * sigf(a0 + b2s[0]);
  float ih1 = colorS[1] * sigf(a1 + b2s[1]);
  float ih2 = colorS[2] * sigf(a2 + b2s[2]);
  float Kv = cwS[0] * ih0 + cwS[1]  * ih1 + cwS[2]  * ih2 + cbS[0];
  float f1 = cwS[3] * ih0 + cwS[4]  * ih1 + cwS[5]  * ih2 + cbS[1];
  float f2 = cwS[6] * ih0 + cwS[7]  * ih1 + cwS[8]  * ih2 + cbS[2];
  float f3 = cwS[9] * ih0 + cwS[10] * ih1 + cwS[11] * ih2 + cbS[3];
  float xc0 = xs[0][py + 2][px + 2];
  float xc1 = xs[1][py + 2][px + 2];
  float xc2 = xs[2][py + 2][px + 2];
  int oi = ((ty0 + py) << 9) + (tx0 + px);
  out[(b * 3 + 0) * HWn + oi] = Kv * xc0 - f1 + xc0;
  out[(b * 3 + 1) * HWn + oi] = Kv * xc1 - f2 + xc1;
  out[(b * 3 + 2) * HWn + oi] = Kv * xc2 - f3 + xc2;
}

// ---- kernel 3: bright = relu(conv3x3(channel-max of reflect-padded x_out)) + histogram L1 ----
__global__ __launch_bounds__(256) void k_bright(
    const float* __restrict__ out, float* __restrict__ bright, unsigned* __restrict__ hist1)
{
  __shared__ float xm[18][18];
  const int tid = threadIdx.x;
  const int tx0 = blockIdx.x * 16, ty0 = blockIdx.y * 16, b = blockIdx.z;
  const int base = b * 3 * HWn;
  for (int i = tid; i < 324; i += 256) {
    int yy = i / 18, xx = i - yy * 18;
    int gy = ty0 - 1 + yy; gy = (gy < 0) ? -gy : (gy > 511 ? 1022 - gy : gy);
    int gx = tx0 - 1 + xx; gx = (gx < 0) ? -gx : (gx > 511 ? 1022 - gx : gx);
    int off = (gy << 9) + gx;
    float v0 = out[base + off];
    float v1 = out[base + HWn + off];
    float v2 = out[base + 2 * HWn + off];
    xm[yy][xx] = fmaxf(v0, fmaxf(v1, v2));
  }
  __syncthreads();
  const int px = tid & 15, py = tid >> 4;
  float s = 0.f;
#pragma unroll
  for (int ky = 0; ky < 3; ++ky)
#pragma unroll
    for (int kx = 0; kx < 3; ++kx) {
      float w = (ky == 1 && kx == 1) ? 1.0f : (1.0f / 9.0f);
      s += xm[py + ky][px + kx] * w;
    }
  s = fmaxf(s, 0.f);
  int gi = b * HWn + ((ty0 + py) << 9) + (tx0 + px);
  bright[gi] = s;
  unsigned bits = __float_as_uint(s);
  atomicAdd(&hist1[(b << 16) + (bits >> 16)], 1u);
}

// ---- kernel 4/6: radix-select within 65536-bin histogram ----
__global__ __launch_bounds__(256) void k_sel1(const unsigned* __restrict__ hist1,
                                              unsigned* __restrict__ selBin,
                                              unsigned* __restrict__ cntAbove)
{
  const int b = blockIdx.x, t = threadIdx.x;
  __shared__ unsigned part[256];
  __shared__ int sT; __shared__ unsigned sA;
  const unsigned* h = hist1 + (b << 16);
  unsigned s = 0;
  for (int i = 0; i < 256; ++i) s += h[(t << 8) + i];
  part[t] = s;
  __syncthreads();
  if (t == 0) {
    unsigned acc = 0; int targ = 0; unsigned above = 0;
    for (int i = 255; i >= 0; --i) {
      if (acc + part[i] >= KTOP) { targ = i; above = acc; break; }
      acc += part[i];
    }
    sT = targ; sA = above;
  }
  __syncthreads();
  if (t == sT) {
    unsigned acc = sA;
    for (int i = 255; i >= 0; --i) {
      unsigned c = h[(t << 8) + i];
      if (acc + c >= KTOP) { selBin[b] = (unsigned)((t << 8) + i); cntAbove[b] = acc; break; }
      acc += c;
    }
  }
}

__global__ __launch_bounds__(256) void k_hist2(const float* __restrict__ bright,
                                               const unsigned* __restrict__ selBin,
                                               unsigned* __restrict__ hist2)
{
  int b = blockIdx.x >> 10;
  int pix = ((blockIdx.x & 1023) << 8) + threadIdx.x;
  unsigned bits = __float_as_uint(bright[b * HWn + pix]);
  if ((bits >> 16) == selBin[b]) atomicAdd(&hist2[(b << 16) + (bits & 0xFFFFu)], 1u);
}

__global__ __launch_bounds__(256) void k_sel2(const unsigned* __restrict__ hist2,
                                              const unsigned* __restrict__ selBin,
                                              const unsigned* __restrict__ cntAbove,
                                              unsigned* __restrict__ Tbits,
                                              unsigned* __restrict__ needEq)
{
  const int b = blockIdx.x, t = threadIdx.x;
  __shared__ unsigned part[256];
  __shared__ int sT; __shared__ unsigned sA;
  const unsigned* h = hist2 + (b << 16);
  const unsigned kp = (unsigned)KTOP - cntAbove[b];
  unsigned s = 0;
  for (int i = 0; i < 256; ++i) s += h[(t << 8) + i];
  part[t] = s;
  __syncthreads();
  if (t == 0) {
    unsigned acc = 0; int targ = 0; unsigned above = 0;
    for (int i = 255; i >= 0; --i) {
      if (acc + part[i] >= kp) { targ = i; above = acc; break; }
      acc += part[i];
    }
    sT = targ; sA = above;
  }
  __syncthreads();
  if (t == sT) {
    unsigned acc = sA;
    for (int i = 255; i >= 0; --i) {
      unsigned c = h[(t << 8) + i];
      if (acc + c >= kp) {
        unsigned low = (unsigned)((t << 8) + i);
        Tbits[b] = (selBin[b] << 16) | low;
        needEq[b] = kp - acc;
        break;
      }
      acc += c;
    }
  }
}

// ---- kernel 7: accumulate picked values. NOTE: reference reshapes (C,H,W)->(H*W,C),
// so pixel i picks flat elements 3i,3i+1,3i+2 of the (C,H,W) block. ----
__global__ __launch_bounds__(256) void k_accum(const float* __restrict__ bright,
                                               const float* __restrict__ out,
                                               const unsigned* __restrict__ Tbits,
                                               const unsigned* __restrict__ needEq,
                                               unsigned* __restrict__ eqTaken,
                                               float* __restrict__ Asum)
{
  int b = blockIdx.x >> 10;
  int pix = ((blockIdx.x & 1023) << 8) + threadIdx.x;
  unsigned bits = __float_as_uint(bright[b * HWn + pix]);
  unsigned T = Tbits[b];
  bool take = bits > T;
  if (bits == T) {
    unsigned old = atomicAdd(&eqTaken[b], 1u);
    take = old < needEq[b];
  }
  float v0 = 0.f, v1 = 0.f, v2 = 0.f;
  if (take) {
    int base = b * 3 * HWn + 3 * pix;
    v0 = out[base];
    v1 = out[base + 1];
    v2 = out[base + 2];
  }
  for (int off = 32; off > 0; off >>= 1) {
    v0 += __shfl_down(v0, off);
    v1 += __shfl_down(v1, off);
    v2 += __shfl_down(v2, off);
  }
  __shared__ float red[4][3];
  int w = threadIdx.x >> 6;
  if ((threadIdx.x & 63) == 0) { red[w][0] = v0; red[w][1] = v1; red[w][2] = v2; }
  __syncthreads();
  if (threadIdx.x == 0) {
    float s0 = red[0][0] + red[1][0] + red[2][0] + red[3][0];
    float s1 = red[0][1] + red[1][1] + red[2][1] + red[3][1];
    float s2 = red[0][2] + red[1][2] + red[2][2] + red[3][2];
    atomicAdd(&Asum[b * 3 + 0], s0);
    atomicAdd(&Asum[b * 3 + 1], s1);
    atomicAdd(&Asum[b * 3 + 2], s2);
  }
}

__global__ void k_final(const float* __restrict__ Asum, float* __restrict__ out) {
  int t = threadIdx.x;
  if (t < 24) out[3 * HWn * 8 + t] = Asum[t] * (1.0f / (float)KTOP);
}

extern "C" void kernel_launch(void* const* d_in, const int* in_sizes, int n_in,
                              void* d_out, int out_size, void* d_ws, size_t ws_size,
                              hipStream_t stream)
{
  const float* x     = (const float*)d_in[0];
  const float* w1    = (const float*)d_in[1];
  const float* b1    = (const float*)d_in[2];
  const float* w2    = (const float*)d_in[3];
  const float* b2    = (const float*)d_in[4];
  const float* cw    = (const float*)d_in[5];
  const float* cb    = (const float*)d_in[6];
  const float* convw = (const float*)d_in[7];
  const float* convb = (const float*)d_in[8];
  float* out = (float*)d_out;
  char* ws = (char*)d_ws;

  // ws layout (bytes):
  float*    bright   = (float*)(ws);               // 8*HW*4   = 8388608
  unsigned* hist1    = (unsigned*)(ws + 8388608);  // 8*65536*4 = 2097152
  unsigned* hist2    = (unsigned*)(ws + 10485760); // 2097152
  float*    Asum     = (float*)(ws + 12582912);    // 96
  unsigned* eqTaken  = (unsigned*)(ws + 12583008); // 32
  float*    means    = (float*)(ws + 12583040);    // 96
  unsigned* selBin   = (unsigned*)(ws + 12583136); // 32
  unsigned* cntAbove = (unsigned*)(ws + 12583168); // 32
  unsigned* Tbits    = (unsigned*)(ws + 12583200); // 32
  unsigned* needEq   = (unsigned*)(ws + 12583232); // 32

  // zero hist1, hist2, Asum, eqTaken, means
  hipMemsetAsync(ws + 8388608, 0, 12583136 - 8388608, stream);

  k_means<<<768, 256, 0, stream>>>(x, means);
  k_fused<<<dim3(32, 32, 8), 256, 0, stream>>>(x, w1, b1, w2, b2, cw, cb, convw, convb, means, out);
  k_bright<<<dim3(32, 32, 8), 256, 0, stream>>>(out, bright, hist1);
  k_sel1<<<8, 256, 0, stream>>>(hist1, selBin, cntAbove);
  k_hist2<<<8192, 256, 0, stream>>>(bright, selBin, hist2);
  k_sel2<<<8, 256, 0, stream>>>(hist2, selBin, cntAbove, Tbits, needEq);
  k_accum<<<8192, 256, 0, stream>>>(bright, out, Tbits, needEq, eqTaken, Asum);
  k_final<<<1, 64, 0, stream>>>(Asum, out);
}

// Round 3
// 925.124 us; speedup vs baseline: 1.8096x; 1.8096x over previous
//
#include <hip/hip_runtime.h>
#include <hip/hip_bf16.h>

#define Hn 512
#define Wn 512
#define HWn (512 * 512)
#define KTOP 26214

__device__ __forceinline__ float sigf(float z) { return 1.0f / (1.0f + __expf(-z)); }

// ---- kernel 1: per (b,c) sums of x (for color) ----
__global__ __launch_bounds__(256) void k_means(const float* __restrict__ x, float* __restrict__ means) {
  int bc = blockIdx.x >> 5;
  int slice = blockIdx.x & 31;
  const float* p = x + bc * HWn + slice * 8192;
  float s = 0.f;
  for (int i = threadIdx.x; i < 8192; i += 256) s += p[i];
  for (int off = 32; off > 0; off >>= 1) s += __shfl_down(s, off);
  if ((threadIdx.x & 63) == 0) atomicAdd(&means[bc], s);
}

// ---- kernel 2: fused conv1+relu+conv2+sigmoid+color+1x1conv+x_out ----
__global__ __launch_bounds__(256) void k_fused(
    const float* __restrict__ x, const float* __restrict__ w1, const float* __restrict__ b1,
    const float* __restrict__ w2, const float* __restrict__ b2,
    const float* __restrict__ cw, const float* __restrict__ cb,
    const float* __restrict__ convw, const float* __restrict__ convb,
    const float* __restrict__ means, float* __restrict__ out)
{
  __shared__ float xs[3][20][20];    // x tile, halo 2 (row stride 20 -> float2-aligned for even cols)
  __shared__ float hsv[324 * 20];    // h chunk: [pixel(18x18)][16 ch + 4 pad] (pad breaks b128 conflicts)
  __shared__ float w1s[64 * 27];
  __shared__ float w2v[9 * 3 * 64];  // [tap][out][ch], float4-aligned per (tap,out,ch16)
  __shared__ float b1s[64];
  __shared__ float b2s[3];
  __shared__ float colorS[3];
  __shared__ float cwS[12];
  __shared__ float cbS[4];

  const int tid = threadIdx.x;
  const int tx0 = blockIdx.x * 16;
  const int ty0 = blockIdx.y * 16;
  const int b   = blockIdx.z;

  for (int i = tid; i < 64 * 27; i += 256) w1s[i] = w1[i];
  for (int i = tid; i < 1728; i += 256) {
    int tap = i / 192, r = i % 192, oc = r / 64, ch = r % 64;
    w2v[i] = w2[oc * 576 + ch * 9 + tap];
  }
  if (tid < 64) b1s[tid] = b1[tid];
  if (tid < 3)  b2s[tid] = b2[tid];
  if (tid < 12) cwS[tid] = convw[tid];
  if (tid < 4)  cbS[tid] = convb[tid];
  if (tid < 3) {
    float z = cb[tid];
    for (int j = 0; j < 3; ++j)
      z += (means[b * 3 + j] * (1.0f / (float)HWn)) * cw[tid * 3 + j];
    colorS[tid] = sigf(z);
  }
  for (int i = tid; i < 1200; i += 256) {
    int c = i / 400, r = i % 400, yy = r / 20, xx = r % 20;
    int gy = ty0 - 2 + yy, gx = tx0 - 2 + xx;
    float v = 0.f;
    if ((unsigned)gy < (unsigned)Hn && (unsigned)gx < (unsigned)Wn)
      v = x[(b * 3 + c) * HWn + (gy << 9) + gx];
    xs[c][yy][xx] = v;
  }
  __syncthreads();

  const int px = tid & 15, py = tid >> 4;   // conv2 output pixel
  const int cl = tid & 15, pg = tid >> 4;   // conv1 channel-in-chunk / pixel-pair group
  float a0 = 0.f, a1 = 0.f, a2 = 0.f;

  for (int cc = 0; cc < 4; ++cc) {
    const int hc = cc * 16 + cl;
    float wr[27];
#pragma unroll
    for (int t = 0; t < 27; ++t) wr[t] = w1s[hc * 27 + t];
    const float bias = b1s[hc];

    // conv1: each thread computes a horizontal PAIR of h-points (shares 18/27 xs reads, float2 LDS)
    for (int q = pg; q < 162; q += 16) {
      int p = q * 2;
      int hy = p / 18, hx = p - hy * 18;      // hx even
      float xv[3][3][4];
#pragma unroll
      for (int ic = 0; ic < 3; ++ic)
#pragma unroll
        for (int ky = 0; ky < 3; ++ky) {
          float2 lo = *(const float2*)&xs[ic][hy + ky][hx];
          float2 hi = *(const float2*)&xs[ic][hy + ky][hx + 2];
          xv[ic][ky][0] = lo.x; xv[ic][ky][1] = lo.y;
          xv[ic][ky][2] = hi.x; xv[ic][ky][3] = hi.y;
        }
      float h0 = bias, h1 = bias;
#pragma unroll
      for (int ic = 0; ic < 3; ++ic)
#pragma unroll
        for (int ky = 0; ky < 3; ++ky)
#pragma unroll
          for (int kx = 0; kx < 3; ++kx) {
            float w = wr[ic * 9 + ky * 3 + kx];
            h0 += xv[ic][ky][kx] * w;
            h1 += xv[ic][ky][kx + 1] * w;
          }
      int gy = ty0 - 1 + hy;
      int gx0 = tx0 - 1 + hx;
      bool vy = (unsigned)gy < (unsigned)Hn;
      h0 = (vy && (unsigned)gx0 < (unsigned)Wn) ? fmaxf(h0, 0.f) : 0.f;
      h1 = (vy && (unsigned)(gx0 + 1) < (unsigned)Wn) ? fmaxf(h1, 0.f) : 0.f;
      hsv[p * 20 + cl] = h0;
      hsv[(p + 1) * 20 + cl] = h1;
    }
    __syncthreads();

    // conv2: h and w2 both stream as float4
#pragma unroll
    for (int ky = 0; ky < 3; ++ky)
#pragma unroll
      for (int kx = 0; kx < 3; ++kx) {
        int tap = ky * 3 + kx;
        int p = (py + ky) * 18 + (px + kx);
        const float4* hp = (const float4*)(hsv + p * 20);
        float4 h4[4];
        h4[0] = hp[0]; h4[1] = hp[1]; h4[2] = hp[2]; h4[3] = hp[3];
#pragma unroll
        for (int oc = 0; oc < 3; ++oc) {
          const float4* wp = (const float4*)(w2v + (tap * 3 + oc) * 64 + cc * 16);
          float s = 0.f;
#pragma unroll
          for (int j = 0; j < 4; ++j) {
            float4 w4 = wp[j];
            s += h4[j].x * w4.x + h4[j].y * w4.y + h4[j].z * w4.z + h4[j].w * w4.w;
          }
          if (oc == 0) a0 += s; else if (oc == 1) a1 += s; else a2 += s;
        }
      }
    __syncthreads();
  }

  float ih0 = colorS[0] * sigf(a0 + b2s[0]);
  float ih1 = colorS[1] * sigf(a1 + b2s[1]);
  float ih2 = colorS[2] * sigf(a2 + b2s[2]);
  float Kv = cwS[0] * ih0 + cwS[1]  * ih1 + cwS[2]  * ih2 + cbS[0];
  float f1 = cwS[3] * ih0 + cwS[4]  * ih1 + cwS[5]  * ih2 + cbS[1];
  float f2 = cwS[6] * ih0 + cwS[7]  * ih1 + cwS[8]  * ih2 + cbS[2];
  float f3 = cwS[9] * ih0 + cwS[10] * ih1 + cwS[11] * ih2 + cbS[3];
  float xc0 = xs[0][py + 2][px + 2];
  float xc1 = xs[1][py + 2][px + 2];
  float xc2 = xs[2][py + 2][px + 2];
  int oi = ((ty0 + py) << 9) + (tx0 + px);
  out[(b * 3 + 0) * HWn + oi] = Kv * xc0 - f1 + xc0;
  out[(b * 3 + 1) * HWn + oi] = Kv * xc1 - f2 + xc1;
  out[(b * 3 + 2) * HWn + oi] = Kv * xc2 - f3 + xc2;
}

// ---- kernel 3: bright + LDS-aggregated level-1 histogram (key = bits>>24) ----
__global__ __launch_bounds__(256) void k_bright(
    const float* __restrict__ out, float* __restrict__ bright, unsigned* __restrict__ h1)
{
  __shared__ float xm[18][18];
  __shared__ unsigned hh[256];
  const int tid = threadIdx.x;
  const int tx0 = blockIdx.x * 16, ty0 = blockIdx.y * 16, b = blockIdx.z;
  const int base = b * 3 * HWn;
  hh[tid] = 0;
  for (int i = tid; i < 324; i += 256) {
    int yy = i / 18, xx = i - yy * 18;
    int gy = ty0 - 1 + yy; gy = (gy < 0) ? -gy : (gy > 511 ? 1022 - gy : gy);
    int gx = tx0 - 1 + xx; gx = (gx < 0) ? -gx : (gx > 511 ? 1022 - gx : gx);
    int off = (gy << 9) + gx;
    float v0 = out[base + off];
    float v1 = out[base + HWn + off];
    float v2 = out[base + 2 * HWn + off];
    xm[yy][xx] = fmaxf(v0, fmaxf(v1, v2));
  }
  __syncthreads();
  const int px = tid & 15, py = tid >> 4;
  float s = 0.f;
#pragma unroll
  for (int ky = 0; ky < 3; ++ky)
#pragma unroll
    for (int kx = 0; kx < 3; ++kx) {
      float w = (ky == 1 && kx == 1) ? 1.0f : (1.0f / 9.0f);
      s += xm[py + ky][px + kx] * w;
    }
  s = fmaxf(s, 0.f);
  int gi = b * HWn + ((ty0 + py) << 9) + (tx0 + px);
  bright[gi] = s;
  atomicAdd(&hh[__float_as_uint(s) >> 24], 1u);
  __syncthreads();
  unsigned c = hh[tid];
  if (c) atomicAdd(&h1[(b << 8) + tid], c);
}

// ---- level-1 select: 256-bin parallel suffix scan ----
__global__ __launch_bounds__(256) void k_sel1(const unsigned* __restrict__ h1,
                                              unsigned* __restrict__ selB1,
                                              unsigned* __restrict__ above1)
{
  const int b = blockIdx.x, t = threadIdx.x;
  __shared__ unsigned s[256];
  s[t] = h1[(b << 8) + t];
  __syncthreads();
  for (int d = 1; d < 256; d <<= 1) {
    unsigned add = (t + d < 256) ? s[t + d] : 0u;
    __syncthreads();
    s[t] += add;
    __syncthreads();
  }
  unsigned mine = s[t];
  unsigned nxt = (t < 255) ? s[t + 1] : 0u;
  if (mine >= KTOP && nxt < KTOP) { selB1[b] = (unsigned)t; above1[b] = nxt; }
}

// ---- level-2 histogram: 12 bits, LDS-aggregated ----
__global__ __launch_bounds__(256) void k_hist12(const float* __restrict__ bright,
                                                const unsigned* __restrict__ selB1,
                                                unsigned* __restrict__ h12)
{
  __shared__ unsigned hh[4096];
  __shared__ int any;
  const int tid = threadIdx.x;
  int b = blockIdx.x >> 10;
  int pix = ((blockIdx.x & 1023) << 8) + tid;
  for (int i = tid; i < 4096; i += 256) hh[i] = 0;
  if (tid == 0) any = 0;
  __syncthreads();
  unsigned bits = __float_as_uint(bright[b * HWn + pix]);
  if ((bits >> 24) == selB1[b]) { atomicAdd(&hh[(bits >> 12) & 0xFFFu], 1u); any = 1; }
  __syncthreads();
  if (any)
    for (int i = tid; i < 4096; i += 256) {
      unsigned c = hh[i];
      if (c) atomicAdd(&h12[(b << 12) + i], c);
    }
}

// ---- level-2 select: 4096-bin segmented suffix scan ----
__global__ __launch_bounds__(256) void k_sel2(const unsigned* __restrict__ h12,
                                              const unsigned* __restrict__ selB1,
                                              const unsigned* __restrict__ above1,
                                              unsigned* __restrict__ P20,
                                              unsigned* __restrict__ above2)
{
  const int b = blockIdx.x, t = threadIdx.x;
  __shared__ unsigned seg[256];
  unsigned loc[16];
  const unsigned kp = (unsigned)KTOP - above1[b];
  unsigned sum = 0;
#pragma unroll
  for (int i = 0; i < 16; ++i) { loc[i] = h12[(b << 12) + t * 16 + i]; sum += loc[i]; }
  seg[t] = sum;
  __syncthreads();
  for (int d = 1; d < 256; d <<= 1) {
    unsigned add = (t + d < 256) ? seg[t + d] : 0u;
    __syncthreads();
    seg[t] += add;
    __syncthreads();
  }
  unsigned mine = seg[t];
  unsigned segAbove = (t < 255) ? seg[t + 1] : 0u;
  if (mine >= kp && segAbove < kp) {
    unsigned acc = segAbove;
    for (int i = 15; i >= 0; --i) {
      unsigned c = loc[i];
      if (acc + c >= kp) {
        P20[b] = (selB1[b] << 12) | (unsigned)(t * 16 + i);
        above2[b] = above1[b] + acc;
        break;
      }
      acc += c;
    }
  }
}

// ---- level-3 histogram: last 12 bits, few matches -> direct global atomics ----
__global__ __launch_bounds__(256) void k_hist3(const float* __restrict__ bright,
                                               const unsigned* __restrict__ P20,
                                               unsigned* __restrict__ h3)
{
  int b = blockIdx.x >> 10;
  int pix = ((blockIdx.x & 1023) << 8) + threadIdx.x;
  unsigned bits = __float_as_uint(bright[b * HWn + pix]);
  if ((bits >> 12) == P20[b]) atomicAdd(&h3[(b << 12) + (bits & 0xFFFu)], 1u);
}

// ---- level-3 select ----
__global__ __launch_bounds__(256) void k_sel3(const unsigned* __restrict__ h3,
                                              const unsigned* __restrict__ P20,
                                              const unsigned* __restrict__ above2,
                                              unsigned* __restrict__ Tbits,
                                              unsigned* __restrict__ needEq)
{
  const int b = blockIdx.x, t = threadIdx.x;
  __shared__ unsigned seg[256];
  unsigned loc[16];
  const unsigned kp = (unsigned)KTOP - above2[b];
  unsigned sum = 0;
#pragma unroll
  for (int i = 0; i < 16; ++i) { loc[i] = h3[(b << 12) + t * 16 + i]; sum += loc[i]; }
  seg[t] = sum;
  __syncthreads();
  for (int d = 1; d < 256; d <<= 1) {
    unsigned add = (t + d < 256) ? seg[t + d] : 0u;
    __syncthreads();
    seg[t] += add;
    __syncthreads();
  }
  unsigned mine = seg[t];
  unsigned segAbove = (t < 255) ? seg[t + 1] : 0u;
  if (mine >= kp && segAbove < kp) {
    unsigned acc = segAbove;
    for (int i = 15; i >= 0; --i) {
      unsigned c = loc[i];
      if (acc + c >= kp) {
        Tbits[b] = (P20[b] << 12) | (unsigned)(t * 16 + i);
        needEq[b] = kp - acc;
        break;
      }
      acc += c;
    }
  }
}

// ---- accumulate picked values (reshape (C,H,W)->(H*W,C): pixel i -> flat 3i,3i+1,3i+2) ----
__global__ __launch_bounds__(256) void k_accum(const float* __restrict__ bright,
                                               const float* __restrict__ out,
                                               const unsigned* __restrict__ Tbits,
                                               const unsigned* __restrict__ needEq,
                                               unsigned* __restrict__ eqTaken,
                                               float* __restrict__ Asum)
{
  int b = blockIdx.x >> 10;
  int pix = ((blockIdx.x & 1023) << 8) + threadIdx.x;
  unsigned bits = __float_as_uint(bright[b * HWn + pix]);
  unsigned T = Tbits[b];
  bool take = bits > T;
  if (bits == T) {
    // pre-read filter caps the same-address atomic storm if ties are numerous
    if (eqTaken[b] < needEq[b]) {
      unsigned old = atomicAdd(&eqTaken[b], 1u);
      take = old < needEq[b];
    }
  }
  float v0 = 0.f, v1 = 0.f, v2 = 0.f;
  if (take) {
    int base = b * 3 * HWn + 3 * pix;
    v0 = out[base];
    v1 = out[base + 1];
    v2 = out[base + 2];
  }
  for (int off = 32; off > 0; off >>= 1) {
    v0 += __shfl_down(v0, off);
    v1 += __shfl_down(v1, off);
    v2 += __shfl_down(v2, off);
  }
  __shared__ float red[4][3];
  int w = threadIdx.x >> 6;
  if ((threadIdx.x & 63) == 0) { red[w][0] = v0; red[w][1] = v1; red[w][2] = v2; }
  __syncthreads();
  if (threadIdx.x == 0) {
    float s0 = red[0][0] + red[1][0] + red[2][0] + red[3][0];
    float s1 = red[0][1] + red[1][1] + red[2][1] + red[3][1];
    float s2 = red[0][2] + red[1][2] + red[2][2] + red[3][2];
    atomicAdd(&Asum[b * 3 + 0], s0);
    atomicAdd(&Asum[b * 3 + 1], s1);
    atomicAdd(&Asum[b * 3 + 2], s2);
  }
}

__global__ void k_final(const float* __restrict__ Asum, float* __restrict__ out) {
  int t = threadIdx.x;
  if (t < 24) out[3 * HWn * 8 + t] = Asum[t] * (1.0f / (float)KTOP);
}

extern "C" void kernel_launch(void* const* d_in, const int* in_sizes, int n_in,
                              void* d_out, int out_size, void* d_ws, size_t ws_size,
                              hipStream_t stream)
{
  const float* x     = (const float*)d_in[0];
  const float* w1    = (const float*)d_in[1];
  const float* b1    = (const float*)d_in[2];
  const float* w2    = (const float*)d_in[3];
  const float* b2    = (const float*)d_in[4];
  const float* cw    = (const float*)d_in[5];
  const float* cb    = (const float*)d_in[6];
  const float* convw = (const float*)d_in[7];
  const float* convb = (const float*)d_in[8];
  float* out = (float*)d_out;
  char* ws = (char*)d_ws;

  float*    bright  = (float*)(ws);                // 8 MB
  unsigned* h1      = (unsigned*)(ws + 8388608);   // 8*256*4   = 8192
  unsigned* h12     = (unsigned*)(ws + 8396800);   // 8*4096*4  = 131072
  unsigned* h3      = (unsigned*)(ws + 8527872);   // 131072
  float*    Asum    = (float*)(ws + 8658944);      // 96
  unsigned* eqTaken = (unsigned*)(ws + 8659040);   // 32
  float*    means   = (float*)(ws + 8659072);      // 96
  unsigned* selB1   = (unsigned*)(ws + 8659168);   // 32
  unsigned* above1  = (unsigned*)(ws + 8659200);   // 32
  unsigned* P20     = (unsigned*)(ws + 8659232);   // 32
  unsigned* above2  = (unsigned*)(ws + 8659264);   // 32
  unsigned* Tbits   = (unsigned*)(ws + 8659296);   // 32
  unsigned* needEq  = (unsigned*)(ws + 8659328);   // 32

  // zero h1, h12, h3, Asum, eqTaken, means
  hipMemsetAsync(ws + 8388608, 0, 8659168 - 8388608, stream);

  k_means<<<768, 256, 0, stream>>>(x, means);
  k_fused<<<dim3(32, 32, 8), 256, 0, stream>>>(x, w1, b1, w2, b2, cw, cb, convw, convb, means, out);
  k_bright<<<dim3(32, 32, 8), 256, 0, stream>>>(out, bright, h1);
  k_sel1<<<8, 256, 0, stream>>>(h1, selB1, above1);
  k_hist12<<<8192, 256, 0, stream>>>(bright, selB1, h12);
  k_sel2<<<8, 256, 0, stream>>>(h12, selB1, above1, P20, above2);
  k_hist3<<<8192, 256, 0, stream>>>(bright, P20, h3);
  k_sel3<<<8, 256, 0, stream>>>(h3, P20, above2, Tbits, needEq);
  k_accum<<<8192, 256, 0, stream>>>(bright, out, Tbits, needEq, eqTaken, Asum);
  k_final<<<1, 64, 0, stream>>>(Asum, out);
}

// Round 4
// 371.155 us; speedup vs baseline: 4.5105x; 2.4926x over previous
//
#include <hip/hip_runtime.h>
#include <hip/hip_bf16.h>

#define Hn 512
#define Wn 512
#define HWn (512 * 512)
#define KTOP 26214

typedef __attribute__((ext_vector_type(8))) short frag_ab;  // 8 bf16
typedef __attribute__((ext_vector_type(4))) float frag_cd;  // 4 fp32

__device__ __forceinline__ float sigf(float z) { return 1.0f / (1.0f + __expf(-z)); }

__device__ __forceinline__ short f2bf(float f) {  // RNE fp32 -> bf16
  unsigned u = __float_as_uint(f);
  u += 0x7FFFu + ((u >> 16) & 1u);
  return (short)(u >> 16);
}

// ---- kernel 1: per (b,c) sums of x (for color) ----
__global__ __launch_bounds__(256) void k_means(const float* __restrict__ x, float* __restrict__ means) {
  int bc = blockIdx.x >> 5;
  int slice = blockIdx.x & 31;
  const float* p = x + bc * HWn + slice * 8192;
  float s = 0.f;
  for (int i = threadIdx.x; i < 8192; i += 256) s += p[i];
  for (int off = 32; off > 0; off >>= 1) s += __shfl_down(s, off);
  if ((threadIdx.x & 63) == 0) atomicAdd(&means[bc], s);
}

// ---- kernel 1b: prebuild MFMA weight fragments + color (once) ----
// w1A: [chunk(4)][lane(64)][8]  A-frag of W1 (16ch x 32k), k=ic*9+tap, k==27 -> bias
// w2A: [step(18)][lane(64)][8]  A-frag of W2 (16oc x 32k), k=tap*64+ch
__global__ __launch_bounds__(256) void k_prep(
    const float* __restrict__ w1, const float* __restrict__ b1,
    const float* __restrict__ w2,
    const float* __restrict__ cw, const float* __restrict__ cb,
    const float* __restrict__ means,
    short* __restrict__ w1A, short* __restrict__ w2A, float* __restrict__ colorG)
{
  const int t = threadIdx.x;
  {
    int chunk = t >> 6, lane = t & 63;
    int m = lane & 15, q = lane >> 4;
    for (int j = 0; j < 8; ++j) {
      int k = q * 8 + j;
      float v = 0.f;
      if (k < 27) v = w1[(chunk * 16 + m) * 27 + k];
      else if (k == 27) v = b1[chunk * 16 + m];
      w1A[t * 8 + j] = f2bf(v);
    }
  }
  for (int i = t; i < 1152; i += 256) {
    int step = i >> 6, lane = i & 63;
    int m = lane & 15, q = lane >> 4;
    int tap = step >> 1, chb = (step & 1) * 32 + q * 8;
    for (int j = 0; j < 8; ++j) {
      int ch = chb + j;
      float v = (m < 3) ? w2[m * 576 + ch * 9 + tap] : 0.f;
      w2A[i * 8 + j] = f2bf(v);
    }
  }
  if (t < 24) {
    int b = t / 3, oc = t % 3;
    float z = cb[oc];
    for (int j = 0; j < 3; ++j)
      z += (means[b * 3 + j] * (1.0f / (float)HWn)) * cw[oc * 3 + j];
    colorG[t] = sigf(z);
  }
}

// ---- kernel 2: fused conv1+relu+conv2+sigmoid+color+1x1conv+x_out via MFMA ----
__global__ __launch_bounds__(256) void k_fused(
    const float* __restrict__ x,
    const float* __restrict__ b2, const float* __restrict__ convw, const float* __restrict__ convb,
    const short* __restrict__ wABg, const float* __restrict__ colorG,
    float* __restrict__ out)
{
  __shared__ float xs[1200];                       // [c][20][20], halo 2, fp32
  __shared__ __align__(16) unsigned short hb[324 * 72];  // h bf16: [pt][ch], stride 72
  __shared__ __align__(16) short wAB[11264];       // w1A (2048) then w2A (9216)
  __shared__ int ptYX[324];
  __shared__ float b2s[3], colorS[3], cwS[12], cbS[4];

  const int tid = threadIdx.x;
  const int wid = tid >> 6, lane = tid & 63;
  const int n = lane & 15, q = lane >> 4;
  const int tx0 = blockIdx.x * 16, ty0 = blockIdx.y * 16;
  const int b = blockIdx.z;

  // stage weights (22528 B = 1408 uint4)
  {
    uint4* dst = (uint4*)wAB;
    const uint4* src = (const uint4*)wABg;
    for (int i = tid; i < 1408; i += 256) dst[i] = src[i];
  }
  // stage x tile
  for (int i = tid; i < 1200; i += 256) {
    int c = i / 400, r = i % 400, yy = r / 20, xx = r % 20;
    int gy = ty0 - 2 + yy, gx = tx0 - 2 + xx;
    float v = 0.f;
    if ((unsigned)gy < (unsigned)Hn && (unsigned)gx < (unsigned)Wn)
      v = x[(b * 3 + c) * HWn + (gy << 9) + gx];
    xs[i] = v;
  }
  for (int i = tid; i < 324; i += 256) ptYX[i] = ((i / 18) << 16) | (i % 18);
  if (tid < 3)  b2s[tid] = b2[tid];
  if (tid < 3)  colorS[tid] = colorG[b * 3 + tid];
  if (tid < 12) cwS[tid] = convw[tid];
  if (tid < 4)  cbS[tid] = convb[tid];

  // per-lane conv1 im2col k-offsets (k = ic*9 + ky*3 + kx; 27=bias row; >27 zero)
  int koff[8];
#pragma unroll
  for (int j = 0; j < 8; ++j) {
    int k = q * 8 + j;
    if (k < 27) { int ic = k / 9; int r = k - ic * 9; koff[j] = ic * 400 + (r / 3) * 20 + (r % 3); }
    else koff[j] = (k == 27) ? -2 : -1;
  }
  __syncthreads();

  // ---- conv1: 21 point-groups x 4 channel-chunks ----
  const frag_ab* w1f = (const frag_ab*)wAB;          // [chunk*64+lane]
  for (int g = wid; g < 21; g += 4) {
    int pt = g * 16 + n;
    bool ptok = pt < 324;
    int ptc = ptok ? pt : 0;
    int yx = ptYX[ptc];
    int pty = yx >> 16, ptx = yx & 0xFFFF;
    int base = pty * 20 + ptx;
    int gy = ty0 - 1 + pty, gx = tx0 - 1 + ptx;
    bool valid = ptok && (unsigned)gy < (unsigned)Hn && (unsigned)gx < (unsigned)Wn;
    frag_ab B;
#pragma unroll
    for (int j = 0; j < 8; ++j) {
      float v = (koff[j] >= 0) ? xs[base + koff[j]] : ((koff[j] == -2) ? 1.0f : 0.0f);
      B[j] = f2bf(v);
    }
#pragma unroll
    for (int ck = 0; ck < 4; ++ck) {
      frag_cd D = {0.f, 0.f, 0.f, 0.f};
      D = __builtin_amdgcn_mfma_f32_16x16x32_bf16(w1f[ck * 64 + lane], B, D, 0, 0, 0);
      if (ptok) {
        float h0 = valid ? fmaxf(D[0], 0.f) : 0.f;
        float h1 = valid ? fmaxf(D[1], 0.f) : 0.f;
        float h2 = valid ? fmaxf(D[2], 0.f) : 0.f;
        float h3 = valid ? fmaxf(D[3], 0.f) : 0.f;
        unsigned lo = (unsigned)(unsigned short)f2bf(h0) | ((unsigned)(unsigned short)f2bf(h1) << 16);
        unsigned hi = (unsigned)(unsigned short)f2bf(h2) | ((unsigned)(unsigned short)f2bf(h3) << 16);
        uint2 v2; v2.x = lo; v2.y = hi;
        *(uint2*)(hb + pt * 72 + ck * 16 + q * 4) = v2;
      }
    }
  }
  __syncthreads();

  // ---- conv2: 4 pixel-rows per wave, 18 K-steps ----
  const frag_ab* w2f = (const frag_ab*)(wAB + 2048); // [step*64+lane]
  frag_cd acc[4];
#pragma unroll
  for (int gg = 0; gg < 4; ++gg) acc[gg] = (frag_cd){0.f, 0.f, 0.f, 0.f};

#pragma unroll
  for (int i = 0; i < 18; ++i) {
    frag_ab A = w2f[i * 64 + lane];
    const int tap = i >> 1, chb = (i & 1) * 32;
    const int ty = tap / 3, tx = tap % 3;
#pragma unroll
    for (int gg = 0; gg < 4; ++gg) {
      int py = wid * 4 + gg;
      int pt = (py + ty) * 18 + (n + tx);
      frag_ab B = *(const frag_ab*)(hb + pt * 72 + chb + q * 8);
      acc[gg] = __builtin_amdgcn_mfma_f32_16x16x32_bf16(A, B, acc[gg], 0, 0, 0);
    }
  }

  // ---- epilogue: lanes 0-15 hold oc0..2 in regs 0..2 ----
  if (q == 0) {
    float c0 = colorS[0], c1 = colorS[1], c2 = colorS[2];
    float bb0 = b2s[0], bb1 = b2s[1], bb2 = b2s[2];
#pragma unroll
    for (int gg = 0; gg < 4; ++gg) {
      int py = wid * 4 + gg;
      float ih0 = c0 * sigf(acc[gg][0] + bb0);
      float ih1 = c1 * sigf(acc[gg][1] + bb1);
      float ih2 = c2 * sigf(acc[gg][2] + bb2);
      float Kv = cwS[0] * ih0 + cwS[1]  * ih1 + cwS[2]  * ih2 + cbS[0];
      float f1 = cwS[3] * ih0 + cwS[4]  * ih1 + cwS[5]  * ih2 + cbS[1];
      float f2 = cwS[6] * ih0 + cwS[7]  * ih1 + cwS[8]  * ih2 + cbS[2];
      float f3 = cwS[9] * ih0 + cwS[10] * ih1 + cwS[11] * ih2 + cbS[3];
      float xc0 = xs[0 * 400 + (py + 2) * 20 + (n + 2)];
      float xc1 = xs[1 * 400 + (py + 2) * 20 + (n + 2)];
      float xc2 = xs[2 * 400 + (py + 2) * 20 + (n + 2)];
      int oi = ((ty0 + py) << 9) + (tx0 + n);
      out[(b * 3 + 0) * HWn + oi] = Kv * xc0 - f1 + xc0;
      out[(b * 3 + 1) * HWn + oi] = Kv * xc1 - f2 + xc1;
      out[(b * 3 + 2) * HWn + oi] = Kv * xc2 - f3 + xc2;
    }
  }
}

// ---- kernel 3: bright + LDS-aggregated level-1 histogram (key = bits>>24) ----
__global__ __launch_bounds__(256) void k_bright(
    const float* __restrict__ out, float* __restrict__ bright, unsigned* __restrict__ h1)
{
  __shared__ float xm[18][18];
  __shared__ unsigned hh[256];
  const int tid = threadIdx.x;
  const int tx0 = blockIdx.x * 16, ty0 = blockIdx.y * 16, b = blockIdx.z;
  const int base = b * 3 * HWn;
  hh[tid] = 0;
  for (int i = tid; i < 324; i += 256) {
    int yy = i / 18, xx = i - yy * 18;
    int gy = ty0 - 1 + yy; gy = (gy < 0) ? -gy : (gy > 511 ? 1022 - gy : gy);
    int gx = tx0 - 1 + xx; gx = (gx < 0) ? -gx : (gx > 511 ? 1022 - gx : gx);
    int off = (gy << 9) + gx;
    float v0 = out[base + off];
    float v1 = out[base + HWn + off];
    float v2 = out[base + 2 * HWn + off];
    xm[yy][xx] = fmaxf(v0, fmaxf(v1, v2));
  }
  __syncthreads();
  const int px = tid & 15, py = tid >> 4;
  float s = 0.f;
#pragma unroll
  for (int ky = 0; ky < 3; ++ky)
#pragma unroll
    for (int kx = 0; kx < 3; ++kx) {
      float w = (ky == 1 && kx == 1) ? 1.0f : (1.0f / 9.0f);
      s += xm[py + ky][px + kx] * w;
    }
  s = fmaxf(s, 0.f);
  int gi = b * HWn + ((ty0 + py) << 9) + (tx0 + px);
  bright[gi] = s;
  atomicAdd(&hh[__float_as_uint(s) >> 24], 1u);
  __syncthreads();
  unsigned c = hh[tid];
  if (c) atomicAdd(&h1[(b << 8) + tid], c);
}

// ---- level-1 select ----
__global__ __launch_bounds__(256) void k_sel1(const unsigned* __restrict__ h1,
                                              unsigned* __restrict__ selB1,
                                              unsigned* __restrict__ above1)
{
  const int b = blockIdx.x, t = threadIdx.x;
  __shared__ unsigned s[256];
  s[t] = h1[(b << 8) + t];
  __syncthreads();
  for (int d = 1; d < 256; d <<= 1) {
    unsigned add = (t + d < 256) ? s[t + d] : 0u;
    __syncthreads();
    s[t] += add;
    __syncthreads();
  }
  unsigned mine = s[t];
  unsigned nxt = (t < 255) ? s[t + 1] : 0u;
  if (mine >= KTOP && nxt < KTOP) { selB1[b] = (unsigned)t; above1[b] = nxt; }
}

// ---- level-2 histogram: grid-stride, 4096 px/block ----
__global__ __launch_bounds__(256) void k_hist12(const float* __restrict__ bright,
                                                const unsigned* __restrict__ selB1,
                                                unsigned* __restrict__ h12)
{
  __shared__ unsigned hh[4096];
  const int tid = threadIdx.x;
  const int b = blockIdx.x >> 6, blk = blockIdx.x & 63;
  for (int i = tid; i < 4096; i += 256) hh[i] = 0;
  __syncthreads();
  const unsigned sb = selB1[b];
  const float4* bp = (const float4*)(bright + b * HWn) + blk * 1024;
#pragma unroll
  for (int it = 0; it < 4; ++it) {
    float4 v = bp[it * 256 + tid];
    unsigned u0 = __float_as_uint(v.x), u1 = __float_as_uint(v.y);
    unsigned u2 = __float_as_uint(v.z), u3 = __float_as_uint(v.w);
    if ((u0 >> 24) == sb) atomicAdd(&hh[(u0 >> 12) & 0xFFFu], 1u);
    if ((u1 >> 24) == sb) atomicAdd(&hh[(u1 >> 12) & 0xFFFu], 1u);
    if ((u2 >> 24) == sb) atomicAdd(&hh[(u2 >> 12) & 0xFFFu], 1u);
    if ((u3 >> 24) == sb) atomicAdd(&hh[(u3 >> 12) & 0xFFFu], 1u);
  }
  __syncthreads();
  for (int i = tid; i < 4096; i += 256) {
    unsigned c = hh[i];
    if (c) atomicAdd(&h12[(b << 12) + i], c);
  }
}

// ---- level-2 select ----
__global__ __launch_bounds__(256) void k_sel2(const unsigned* __restrict__ h12,
                                              const unsigned* __restrict__ selB1,
                                              const unsigned* __restrict__ above1,
                                              unsigned* __restrict__ P20,
                                              unsigned* __restrict__ above2)
{
  const int b = blockIdx.x, t = threadIdx.x;
  __shared__ unsigned seg[256];
  unsigned loc[16];
  const unsigned kp = (unsigned)KTOP - above1[b];
  unsigned sum = 0;
#pragma unroll
  for (int i = 0; i < 16; ++i) { loc[i] = h12[(b << 12) + t * 16 + i]; sum += loc[i]; }
  seg[t] = sum;
  __syncthreads();
  for (int d = 1; d < 256; d <<= 1) {
    unsigned add = (t + d < 256) ? seg[t + d] : 0u;
    __syncthreads();
    seg[t] += add;
    __syncthreads();
  }
  unsigned mine = seg[t];
  unsigned segAbove = (t < 255) ? seg[t + 1] : 0u;
  if (mine >= kp && segAbove < kp) {
    unsigned acc = segAbove;
    for (int i = 15; i >= 0; --i) {
      unsigned c = loc[i];
      if (acc + c >= kp) {
        P20[b] = (selB1[b] << 12) | (unsigned)(t * 16 + i);
        above2[b] = above1[b] + acc;
        break;
      }
      acc += c;
    }
  }
}

// ---- level-3 histogram: grid-stride, direct global atomics (rare) ----
__global__ __launch_bounds__(256) void k_hist3(const float* __restrict__ bright,
                                               const unsigned* __restrict__ P20,
                                               unsigned* __restrict__ h3)
{
  const int tid = threadIdx.x;
  const int b = blockIdx.x >> 6, blk = blockIdx.x & 63;
  const unsigned p20 = P20[b];
  const float4* bp = (const float4*)(bright + b * HWn) + blk * 1024;
#pragma unroll
  for (int it = 0; it < 4; ++it) {
    float4 v = bp[it * 256 + tid];
    unsigned u0 = __float_as_uint(v.x), u1 = __float_as_uint(v.y);
    unsigned u2 = __float_as_uint(v.z), u3 = __float_as_uint(v.w);
    if ((u0 >> 12) == p20) atomicAdd(&h3[(b << 12) + (u0 & 0xFFFu)], 1u);
    if ((u1 >> 12) == p20) atomicAdd(&h3[(b << 12) + (u1 & 0xFFFu)], 1u);
    if ((u2 >> 12) == p20) atomicAdd(&h3[(b << 12) + (u2 & 0xFFFu)], 1u);
    if ((u3 >> 12) == p20) atomicAdd(&h3[(b << 12) + (u3 & 0xFFFu)], 1u);
  }
}

// ---- level-3 select ----
__global__ __launch_bounds__(256) void k_sel3(const unsigned* __restrict__ h3,
                                              const unsigned* __restrict__ P20,
                                              const unsigned* __restrict__ above2,
                                              unsigned* __restrict__ Tbits,
                                              unsigned* __restrict__ needEq)
{
  const int b = blockIdx.x, t = threadIdx.x;
  __shared__ unsigned seg[256];
  unsigned loc[16];
  const unsigned kp = (unsigned)KTOP - above2[b];
  unsigned sum = 0;
#pragma unroll
  for (int i = 0; i < 16; ++i) { loc[i] = h3[(b << 12) + t * 16 + i]; sum += loc[i]; }
  seg[t] = sum;
  __syncthreads();
  for (int d = 1; d < 256; d <<= 1) {
    unsigned add = (t + d < 256) ? seg[t + d] : 0u;
    __syncthreads();
    seg[t] += add;
    __syncthreads();
  }
  unsigned mine = seg[t];
  unsigned segAbove = (t < 255) ? seg[t + 1] : 0u;
  if (mine >= kp && segAbove < kp) {
    unsigned acc = segAbove;
    for (int i = 15; i >= 0; --i) {
      unsigned c = loc[i];
      if (acc + c >= kp) {
        Tbits[b] = (P20[b] << 12) | (unsigned)(t * 16 + i);
        needEq[b] = kp - acc;
        break;
      }
      acc += c;
    }
  }
}

// ---- accumulate picked values (pixel i -> flat 3i,3i+1,3i+2 of (C,H,W) block) ----
__global__ __launch_bounds__(256) void k_accum(const float* __restrict__ bright,
                                               const float* __restrict__ out,
                                               const unsigned* __restrict__ Tbits,
                                               const unsigned* __restrict__ needEq,
                                               unsigned* __restrict__ eqTaken,
                                               float* __restrict__ Asum)
{
  const int tid = threadIdx.x;
  const int b = blockIdx.x >> 6, blk = blockIdx.x & 63;
  const unsigned T = Tbits[b];
  const unsigned ne = needEq[b];
  const float* op = out + b * 3 * HWn;
  float v0 = 0.f, v1 = 0.f, v2 = 0.f;
  for (int it = 0; it < 16; ++it) {
    int pix = blk * 4096 + it * 256 + tid;
    unsigned bits = __float_as_uint(bright[b * HWn + pix]);
    bool take = bits > T;
    if (bits == T) {
      if (eqTaken[b] < ne) {
        unsigned old = atomicAdd(&eqTaken[b], 1u);
        take = old < ne;
      }
    }
    if (take) {
      v0 += op[3 * pix];
      v1 += op[3 * pix + 1];
      v2 += op[3 * pix + 2];
    }
  }
  for (int off = 32; off > 0; off >>= 1) {
    v0 += __shfl_down(v0, off);
    v1 += __shfl_down(v1, off);
    v2 += __shfl_down(v2, off);
  }
  __shared__ float red[4][3];
  int w = tid >> 6;
  if ((tid & 63) == 0) { red[w][0] = v0; red[w][1] = v1; red[w][2] = v2; }
  __syncthreads();
  if (tid == 0) {
    float s0 = red[0][0] + red[1][0] + red[2][0] + red[3][0];
    float s1 = red[0][1] + red[1][1] + red[2][1] + red[3][1];
    float s2 = red[0][2] + red[1][2] + red[2][2] + red[3][2];
    atomicAdd(&Asum[b * 3 + 0], s0);
    atomicAdd(&Asum[b * 3 + 1], s1);
    atomicAdd(&Asum[b * 3 + 2], s2);
  }
}

__global__ void k_final(const float* __restrict__ Asum, float* __restrict__ out) {
  int t = threadIdx.x;
  if (t < 24) out[3 * HWn * 8 + t] = Asum[t] * (1.0f / (float)KTOP);
}

extern "C" void kernel_launch(void* const* d_in, const int* in_sizes, int n_in,
                              void* d_out, int out_size, void* d_ws, size_t ws_size,
                              hipStream_t stream)
{
  const float* x     = (const float*)d_in[0];
  const float* w1    = (const float*)d_in[1];
  const float* b1    = (const float*)d_in[2];
  const float* w2    = (const float*)d_in[3];
  const float* b2    = (const float*)d_in[4];
  const float* cw    = (const float*)d_in[5];
  const float* cb    = (const float*)d_in[6];
  const float* convw = (const float*)d_in[7];
  const float* convb = (const float*)d_in[8];
  float* out = (float*)d_out;
  char* ws = (char*)d_ws;

  float*    bright  = (float*)(ws);                // 8 MB
  unsigned* h1      = (unsigned*)(ws + 8388608);   // 8*256*4 = 8192
  unsigned* h12     = (unsigned*)(ws + 8396800);   // 131072
  unsigned* h3      = (unsigned*)(ws + 8527872);   // 131072
  float*    Asum    = (float*)(ws + 8658944);      // 96
  unsigned* eqTaken = (unsigned*)(ws + 8659040);   // 32
  float*    means   = (float*)(ws + 8659072);      // 96
  unsigned* selB1   = (unsigned*)(ws + 8659168);   // 32
  unsigned* above1  = (unsigned*)(ws + 8659200);   // 32
  unsigned* P20     = (unsigned*)(ws + 8659232);   // 32
  unsigned* above2  = (unsigned*)(ws + 8659264);   // 32
  unsigned* Tbits   = (unsigned*)(ws + 8659296);   // 32
  unsigned* needEq  = (unsigned*)(ws + 8659328);   // 32
  short*    w1Ag    = (short*)(ws + 8659360);      // 2048 shorts = 4096 B (16-aligned)
  short*    w2Ag    = (short*)(ws + 8663456);      // 9216 shorts = 18432 B
  float*    colorG  = (float*)(ws + 8681888);      // 96

  // zero h1, h12, h3, Asum, eqTaken, means
  hipMemsetAsync(ws + 8388608, 0, 8659168 - 8388608, stream);

  k_means<<<768, 256, 0, stream>>>(x, means);
  k_prep<<<1, 256, 0, stream>>>(w1, b1, w2, cw, cb, means, w1Ag, w2Ag, colorG);
  k_fused<<<dim3(32, 32, 8), 256, 0, stream>>>(x, b2, convw, convb, w1Ag, colorG, out);
  k_bright<<<dim3(32, 32, 8), 256, 0, stream>>>(out, bright, h1);
  k_sel1<<<8, 256, 0, stream>>>(h1, selB1, above1);
  k_hist12<<<512, 256, 0, stream>>>(bright, selB1, h12);
  k_sel2<<<8, 256, 0, stream>>>(h12, selB1, above1, P20, above2);
  k_hist3<<<512, 256, 0, stream>>>(bright, P20, h3);
  k_sel3<<<8, 256, 0, stream>>>(h3, P20, above2, Tbits, needEq);
  k_accum<<<512, 256, 0, stream>>>(bright, out, Tbits, needEq, eqTaken, Asum);
  k_final<<<1, 64, 0, stream>>>(Asum, out);
}

// Round 5
// 329.854 us; speedup vs baseline: 5.0753x; 1.1252x over previous
//
#include <hip/hip_runtime.h>
#include <hip/hip_bf16.h>

#define Hn 512
#define Wn 512
#define HWn (512 * 512)
#define KTOP 26214

typedef __attribute__((ext_vector_type(8))) short frag_ab;  // 8 bf16
typedef __attribute__((ext_vector_type(4))) float frag_cd;  // 4 fp32

__device__ __forceinline__ float sigf(float z) { return 1.0f / (1.0f + __expf(-z)); }

__device__ __forceinline__ short f2bf(float f) {  // RNE fp32 -> bf16
  unsigned u = __float_as_uint(f);
  u += 0x7FFFu + ((u >> 16) & 1u);
  return (short)(u >> 16);
}

// ---- kernel 1: per (b,c) sums of x (color) + last-block runs weight-frag prep ----
__global__ __launch_bounds__(256) void k_means(
    const float* __restrict__ x, float* __restrict__ means, unsigned* __restrict__ doneCnt,
    const float* __restrict__ w1, const float* __restrict__ b1, const float* __restrict__ w2,
    const float* __restrict__ cw, const float* __restrict__ cb,
    short* __restrict__ w1A, short* __restrict__ w2A, float* __restrict__ colorG)
{
  const int tid = threadIdx.x;
  __shared__ int lastS;
  int bc = blockIdx.x >> 5;
  int slice = blockIdx.x & 31;
  const float4* p = (const float4*)(x + bc * HWn + slice * 8192);
  float s = 0.f;
  for (int i = tid; i < 2048; i += 256) { float4 v = p[i]; s += v.x + v.y + v.z + v.w; }
  for (int off = 32; off > 0; off >>= 1) s += __shfl_down(s, off);
  if ((tid & 63) == 0) { atomicAdd(&means[bc], s); __threadfence(); }
  __syncthreads();
  if (tid == 0) { unsigned tk = atomicAdd(doneCnt, 1u); lastS = (tk == 767); }
  __syncthreads();
  if (!lastS) return;

  // ---- prep (runs once, after all means complete) ----
  {
    int chunk = tid >> 6, lane = tid & 63;
    int m = lane & 15, q = lane >> 4;
    for (int j = 0; j < 8; ++j) {
      int k = q * 8 + j;
      float v = 0.f;
      if (k < 27) v = w1[(chunk * 16 + m) * 27 + k];
      else if (k == 27) v = b1[chunk * 16 + m];
      w1A[tid * 8 + j] = f2bf(v);
    }
  }
  for (int i = tid; i < 1152; i += 256) {
    int step = i >> 6, lane = i & 63;
    int m = lane & 15, q = lane >> 4;
    int tap = step >> 1, chb = (step & 1) * 32 + q * 8;
    for (int j = 0; j < 8; ++j) {
      int ch = chb + j;
      float v = (m < 3) ? w2[m * 576 + ch * 9 + tap] : 0.f;
      w2A[i * 8 + j] = f2bf(v);
    }
  }
  if (tid < 24) {
    int b = tid / 3, oc = tid % 3;
    float z = cb[oc];
    for (int j = 0; j < 3; ++j)
      z += (atomicAdd(&means[b * 3 + j], 0.f) * (1.0f / (float)HWn)) * cw[oc * 3 + j];
    colorG[tid] = sigf(z);
  }
}

// ---- kernel 2: fused conv1+relu+conv2+sigmoid+color+1x1conv+x_out via MFMA ----
__global__ __launch_bounds__(256, 3) void k_fused(
    const float* __restrict__ x,
    const float* __restrict__ b2, const float* __restrict__ convw, const float* __restrict__ convb,
    const short* __restrict__ w1Ag, const short* __restrict__ w2Ag,
    const float* __restrict__ colorG, float* __restrict__ out)
{
  __shared__ __align__(16) float xs[1200];              // [c][20][20] halo-2, bf16-rounded fp32
  __shared__ __align__(16) unsigned short hb[324 * 72]; // h bf16: [pt][ch], stride 72
  __shared__ float b2s[3], colorS[3], cwS[12], cbS[4];

  const int tid = threadIdx.x;
  const int wid = tid >> 6, lane = tid & 63;
  const int n = lane & 15, q = lane >> 4;
  const int tx0 = blockIdx.x * 16, ty0 = blockIdx.y * 16;
  const int b = blockIdx.z;

  for (int i = tid; i < 1200; i += 256) {
    int c = i / 400, r = i % 400, yy = r / 20, xx = r % 20;
    int gy = ty0 - 2 + yy, gx = tx0 - 2 + xx;
    float v = 0.f;
    if ((unsigned)gy < 512u && (unsigned)gx < 512u)
      v = __bfloat162float(__float2bfloat16(x[(b * 3 + c) * HWn + (gy << 9) + gx]));
    xs[i] = v;
  }
  if (tid < 3)  b2s[tid] = b2[tid];
  if (tid < 3)  colorS[tid] = colorG[b * 3 + tid];
  if (tid < 12) cwS[tid] = convw[tid];
  if (tid < 4)  cbS[tid] = convb[tid];

  frag_ab w1f[4];
#pragma unroll
  for (int ck = 0; ck < 4; ++ck) w1f[ck] = *(const frag_ab*)(w1Ag + (ck * 64 + lane) * 8);

  // conv1 im2col k-offsets as byte offsets to the HIGH u16 of the fp32 (== bf16)
  int kb[8], kf[8];  // kf: 0=read, 1=bf16(1.0), 2=zero
#pragma unroll
  for (int j = 0; j < 8; ++j) {
    int k = q * 8 + j;
    if (k < 27) { int ic = k / 9; int r = k - ic * 9; kb[j] = (ic * 400 + (r / 3) * 20 + (r % 3)) * 4 + 2; kf[j] = 0; }
    else if (k == 27) { kb[j] = 0; kf[j] = 1; }
    else { kb[j] = 0; kf[j] = 2; }
  }
  __syncthreads();

  // ---- conv1: 21 point-groups x 4 channel-chunks ----
  for (int g = wid; g < 21; g += 4) {
    int pt = g * 16 + n;
    bool ptok = pt < 324;
    int ptc = ptok ? pt : 0;
    int pty = (ptc * 3641) >> 16;  // /18 exact for pt<324
    int ptx = ptc - pty * 18;
    int baseB = (pty * 20 + ptx) * 4;
    int gy = ty0 - 1 + pty, gx = tx0 - 1 + ptx;
    bool valid = ptok && (unsigned)gy < 512u && (unsigned)gx < 512u;
    frag_ab B;
#pragma unroll
    for (int j = 0; j < 8; ++j) {
      short v;
      if (kf[j] == 0) v = *(const short*)((const char*)xs + baseB + kb[j]);
      else v = (kf[j] == 1) ? (short)0x3F80 : (short)0;
      B[j] = v;
    }
#pragma unroll
    for (int ck = 0; ck < 4; ++ck) {
      frag_cd D = {0.f, 0.f, 0.f, 0.f};
      D = __builtin_amdgcn_mfma_f32_16x16x32_bf16(w1f[ck], B, D, 0, 0, 0);
      if (ptok) {
        float h0 = valid ? fmaxf(D[0], 0.f) : 0.f;
        float h1 = valid ? fmaxf(D[1], 0.f) : 0.f;
        float h2 = valid ? fmaxf(D[2], 0.f) : 0.f;
        float h3 = valid ? fmaxf(D[3], 0.f) : 0.f;
        unsigned lo = (unsigned)(unsigned short)f2bf(h0) | ((unsigned)(unsigned short)f2bf(h1) << 16);
        unsigned hi = (unsigned)(unsigned short)f2bf(h2) | ((unsigned)(unsigned short)f2bf(h3) << 16);
        uint2 v2; v2.x = lo; v2.y = hi;
        *(uint2*)(hb + pt * 72 + ck * 16 + q * 4) = v2;
      }
    }
  }
  __syncthreads();

  // ---- conv2: 4 pixel-rows per wave, 18 K-steps, A-frags from global (L2-hot) ----
  const int pbase = wid * 4 * 18 + n;
  frag_cd acc[4];
#pragma unroll
  for (int gg = 0; gg < 4; ++gg) acc[gg] = (frag_cd){0.f, 0.f, 0.f, 0.f};

#pragma unroll 6
  for (int i = 0; i < 18; ++i) {
    frag_ab A = *(const frag_ab*)(w2Ag + (i * 64 + lane) * 8);
    int tap = i >> 1;
    int ty = (tap * 11) >> 5;         // /3 exact for tap<9
    int tx = tap - ty * 3;
    int chbyte = (i & 1) * 64 + q * 16;
    int pt0 = pbase + ty * 18 + tx;
#pragma unroll
    for (int gg = 0; gg < 4; ++gg) {
      frag_ab Bf = *(const frag_ab*)((const char*)hb + (pt0 + gg * 18) * 144 + chbyte);
      acc[gg] = __builtin_amdgcn_mfma_f32_16x16x32_bf16(A, Bf, acc[gg], 0, 0, 0);
    }
  }

  // ---- epilogue: lanes q==0 hold oc0..2 in regs 0..2 ----
  if (q == 0) {
    float c0 = colorS[0], c1 = colorS[1], c2 = colorS[2];
    float bb0 = b2s[0], bb1 = b2s[1], bb2 = b2s[2];
#pragma unroll
    for (int gg = 0; gg < 4; ++gg) {
      int py = wid * 4 + gg;
      float ih0 = c0 * sigf(acc[gg][0] + bb0);
      float ih1 = c1 * sigf(acc[gg][1] + bb1);
      float ih2 = c2 * sigf(acc[gg][2] + bb2);
      float Kv = cwS[0] * ih0 + cwS[1]  * ih1 + cwS[2]  * ih2 + cbS[0];
      float f1 = cwS[3] * ih0 + cwS[4]  * ih1 + cwS[5]  * ih2 + cbS[1];
      float f2 = cwS[6] * ih0 + cwS[7]  * ih1 + cwS[8]  * ih2 + cbS[2];
      float f3 = cwS[9] * ih0 + cwS[10] * ih1 + cwS[11] * ih2 + cbS[3];
      float xc0 = xs[0 * 400 + (py + 2) * 20 + (n + 2)];
      float xc1 = xs[1 * 400 + (py + 2) * 20 + (n + 2)];
      float xc2 = xs[2 * 400 + (py + 2) * 20 + (n + 2)];
      int oi = ((ty0 + py) << 9) + (tx0 + n);
      out[(b * 3 + 0) * HWn + oi] = Kv * xc0 - f1 + xc0;
      out[(b * 3 + 1) * HWn + oi] = Kv * xc1 - f2 + xc1;
      out[(b * 3 + 2) * HWn + oi] = Kv * xc2 - f3 + xc2;
    }
  }
}

// ---- kernel 3: bright (4-row strips, vectorized) + 256-bin L1 hist ----
__global__ __launch_bounds__(256) void k_bright(
    const float* __restrict__ out, float* __restrict__ bright, unsigned* __restrict__ h1)
{
  __shared__ __align__(16) float xm[6][516];
  __shared__ unsigned hh[256];
  const int tid = threadIdx.x;
  const int y0 = blockIdx.x * 4;
  const int b = blockIdx.y;
  const float* op = out + b * 3 * HWn;
  hh[tid] = 0;
  for (int idx = tid; idx < 768; idx += 256) {
    int r = idx >> 7, seg = idx & 127;
    int gy = y0 - 1 + r; gy = (gy < 0) ? -gy : (gy > 511 ? 1022 - gy : gy);
    int c0 = seg * 4;
    float4 v0 = *(const float4*)(op + (gy << 9) + c0);
    float4 v1 = *(const float4*)(op + HWn + (gy << 9) + c0);
    float4 v2 = *(const float4*)(op + 2 * HWn + (gy << 9) + c0);
    xm[r][c0 + 1] = fmaxf(v0.x, fmaxf(v1.x, v2.x));
    xm[r][c0 + 2] = fmaxf(v0.y, fmaxf(v1.y, v2.y));
    xm[r][c0 + 3] = fmaxf(v0.z, fmaxf(v1.z, v2.z));
    xm[r][c0 + 4] = fmaxf(v0.w, fmaxf(v1.w, v2.w));
  }
  if (tid < 12) {
    int r = tid >> 1, side = tid & 1;
    int gy = y0 - 1 + r; gy = (gy < 0) ? -gy : (gy > 511 ? 1022 - gy : gy);
    int gx = side ? 510 : 1;  // reflect of col 512 / col -1
    float m = fmaxf(op[(gy << 9) + gx], fmaxf(op[HWn + (gy << 9) + gx], op[2 * HWn + (gy << 9) + gx]));
    xm[r][side ? 513 : 0] = m;
  }
  __syncthreads();
  const int r = tid >> 6, c0 = (tid & 63) * 8;
  const float* x0 = &xm[r][c0];
  const float* x1 = &xm[r + 1][c0];
  const float* x2 = &xm[r + 2][c0];
  float r0[10], r1[10], r2[10];
  { float4 a = *(const float4*)x0, c = *(const float4*)(x0 + 4); float2 e = *(const float2*)(x0 + 8);
    r0[0]=a.x; r0[1]=a.y; r0[2]=a.z; r0[3]=a.w; r0[4]=c.x; r0[5]=c.y; r0[6]=c.z; r0[7]=c.w; r0[8]=e.x; r0[9]=e.y; }
  { float4 a = *(const float4*)x1, c = *(const float4*)(x1 + 4); float2 e = *(const float2*)(x1 + 8);
    r1[0]=a.x; r1[1]=a.y; r1[2]=a.z; r1[3]=a.w; r1[4]=c.x; r1[5]=c.y; r1[6]=c.z; r1[7]=c.w; r1[8]=e.x; r1[9]=e.y; }
  { float4 a = *(const float4*)x2, c = *(const float4*)(x2 + 4); float2 e = *(const float2*)(x2 + 8);
    r2[0]=a.x; r2[1]=a.y; r2[2]=a.z; r2[3]=a.w; r2[4]=c.x; r2[5]=c.y; r2[6]=c.z; r2[7]=c.w; r2[8]=e.x; r2[9]=e.y; }
  float cs[10];
#pragma unroll
  for (int i = 0; i < 10; ++i) cs[i] = r0[i] + r1[i] + r2[i];
  float res[8];
#pragma unroll
  for (int i = 0; i < 8; ++i) {
    float s = (cs[i] + cs[i + 1] + cs[i + 2]) * (1.f / 9.f) + r1[i + 1] * (8.f / 9.f);
    s = fmaxf(s, 0.f);
    res[i] = s;
    atomicAdd(&hh[__float_as_uint(s) >> 24], 1u);
  }
  int gbase = b * HWn + ((y0 + r) << 9) + c0;
  *(float4*)(bright + gbase)     = make_float4(res[0], res[1], res[2], res[3]);
  *(float4*)(bright + gbase + 4) = make_float4(res[4], res[5], res[6], res[7]);
  __syncthreads();
  unsigned c = hh[tid];
  if (c) atomicAdd(&h1[(b << 8) + tid], c);
}

// ---- in-block selection helpers (hist is globally complete when these run) ----
__device__ void sel256(const unsigned* __restrict__ h, unsigned kneed,
                       unsigned* sm, unsigned* oBin, unsigned* oAbove)
{
  const int t = threadIdx.x;
  sm[t] = h[t];
  __syncthreads();
  for (int d = 1; d < 256; d <<= 1) {
    unsigned add = (t + d < 256) ? sm[t + d] : 0u;
    __syncthreads();
    sm[t] += add;
    __syncthreads();
  }
  unsigned mine = sm[t];
  unsigned nxt = (t < 255) ? sm[t + 1] : 0u;
  if (mine >= kneed && nxt < kneed) { *oBin = (unsigned)t; *oAbove = nxt; }
  __syncthreads();
}

__device__ void sel4096(const unsigned* __restrict__ h, unsigned kneed,
                        unsigned* sm, unsigned* oBin, unsigned* oAbove)
{
  const int t = threadIdx.x;
  unsigned loc[16]; unsigned sum = 0;
#pragma unroll
  for (int i = 0; i < 16; ++i) { loc[i] = h[t * 16 + i]; sum += loc[i]; }
  sm[t] = sum;
  __syncthreads();
  for (int d = 1; d < 256; d <<= 1) {
    unsigned add = (t + d < 256) ? sm[t + d] : 0u;
    __syncthreads();
    sm[t] += add;
    __syncthreads();
  }
  unsigned mine = sm[t];
  unsigned nxt = (t < 255) ? sm[t + 1] : 0u;
  if (mine >= kneed && nxt < kneed) {
    unsigned acc = nxt;
    for (int i = 15; i >= 0; --i) {
      unsigned c = loc[i];
      if (acc + c >= kneed) { *oBin = (unsigned)(t * 16 + i); *oAbove = acc; break; }
      acc += c;
    }
  }
  __syncthreads();
}

// ---- level-2 histogram (sel1 inline) ----
__global__ __launch_bounds__(256) void k_hist12(const float* __restrict__ bright,
                                                const unsigned* __restrict__ h1,
                                                unsigned* __restrict__ h12)
{
  __shared__ unsigned hh[4096];
  __shared__ unsigned sm[256];
  __shared__ unsigned sB1, sA1;
  const int tid = threadIdx.x;
  const int b = blockIdx.x >> 6, blk = blockIdx.x & 63;
  sel256(h1 + (b << 8), KTOP, sm, &sB1, &sA1);
  for (int i = tid; i < 4096; i += 256) hh[i] = 0;
  __syncthreads();
  const unsigned sb = sB1;
  const float4* bp = (const float4*)(bright + b * HWn) + blk * 1024;
#pragma unroll
  for (int it = 0; it < 4; ++it) {
    float4 v = bp[it * 256 + tid];
    unsigned u0 = __float_as_uint(v.x), u1 = __float_as_uint(v.y);
    unsigned u2 = __float_as_uint(v.z), u3 = __float_as_uint(v.w);
    if ((u0 >> 24) == sb) atomicAdd(&hh[(u0 >> 12) & 0xFFFu], 1u);
    if ((u1 >> 24) == sb) atomicAdd(&hh[(u1 >> 12) & 0xFFFu], 1u);
    if ((u2 >> 24) == sb) atomicAdd(&hh[(u2 >> 12) & 0xFFFu], 1u);
    if ((u3 >> 24) == sb) atomicAdd(&hh[(u3 >> 12) & 0xFFFu], 1u);
  }
  __syncthreads();
  for (int i = tid; i < 4096; i += 256) {
    unsigned c = hh[i];
    if (c) atomicAdd(&h12[(b << 12) + i], c);
  }
}

// ---- level-3 histogram (sel1+sel2 inline) ----
__global__ __launch_bounds__(256) void k_hist3(const float* __restrict__ bright,
                                               const unsigned* __restrict__ h1,
                                               const unsigned* __restrict__ h12,
                                               unsigned* __restrict__ h3)
{
  __shared__ unsigned sm[256];
  __shared__ unsigned sB1, sA1, sB2, sA2;
  const int tid = threadIdx.x;
  const int b = blockIdx.x >> 6, blk = blockIdx.x & 63;
  sel256(h1 + (b << 8), KTOP, sm, &sB1, &sA1);
  sel4096(h12 + (b << 12), KTOP - sA1, sm, &sB2, &sA2);
  const unsigned P20 = (sB1 << 12) | sB2;
  const float4* bp = (const float4*)(bright + b * HWn) + blk * 1024;
#pragma unroll
  for (int it = 0; it < 4; ++it) {
    float4 v = bp[it * 256 + tid];
    unsigned u0 = __float_as_uint(v.x), u1 = __float_as_uint(v.y);
    unsigned u2 = __float_as_uint(v.z), u3 = __float_as_uint(v.w);
    if ((u0 >> 12) == P20) atomicAdd(&h3[(b << 12) + (u0 & 0xFFFu)], 1u);
    if ((u1 >> 12) == P20) atomicAdd(&h3[(b << 12) + (u1 & 0xFFFu)], 1u);
    if ((u2 >> 12) == P20) atomicAdd(&h3[(b << 12) + (u2 & 0xFFFu)], 1u);
    if ((u3 >> 12) == P20) atomicAdd(&h3[(b << 12) + (u3 & 0xFFFu)], 1u);
  }
}

// ---- accumulate (sel1+sel2+sel3 inline; last block writes A) ----
__global__ __launch_bounds__(256) void k_accum(const float* __restrict__ bright,
                                               const float* __restrict__ outv,
                                               const unsigned* __restrict__ h1,
                                               const unsigned* __restrict__ h12,
                                               const unsigned* __restrict__ h3,
                                               unsigned* __restrict__ eqTaken,
                                               float* __restrict__ Asum,
                                               unsigned* __restrict__ doneCnt,
                                               float* __restrict__ out)
{
  __shared__ unsigned sm[256];
  __shared__ unsigned sB1, sA1, sB2, sA2, sB3, sA3;
  __shared__ float red[4][3];
  __shared__ int lastA;
  const int tid = threadIdx.x;
  const int b = blockIdx.x >> 6, blk = blockIdx.x & 63;
  sel256(h1 + (b << 8), KTOP, sm, &sB1, &sA1);
  sel4096(h12 + (b << 12), KTOP - sA1, sm, &sB2, &sA2);
  const unsigned above2 = sA1 + sA2;
  sel4096(h3 + (b << 12), KTOP - above2, sm, &sB3, &sA3);
  const unsigned T = ((((sB1 << 12) | sB2) << 12)) | sB3;
  const unsigned ne = (KTOP - above2) - sA3;

  const float* op = outv + b * 3 * HWn;
  float v0 = 0.f, v1 = 0.f, v2 = 0.f;
  for (int it = 0; it < 16; ++it) {
    int pix = blk * 4096 + it * 256 + tid;
    unsigned bits = __float_as_uint(bright[b * HWn + pix]);
    bool take = bits > T;
    if (bits == T) {
      if (eqTaken[b] < ne) {
        unsigned old = atomicAdd(&eqTaken[b], 1u);
        take = old < ne;
      }
    }
    if (take) {  // reshape (C,H,W)->(H*W,C): pixel i -> flat 3i,3i+1,3i+2
      v0 += op[3 * pix];
      v1 += op[3 * pix + 1];
      v2 += op[3 * pix + 2];
    }
  }
  for (int off = 32; off > 0; off >>= 1) {
    v0 += __shfl_down(v0, off);
    v1 += __shfl_down(v1, off);
    v2 += __shfl_down(v2, off);
  }
  int w = tid >> 6;
  if ((tid & 63) == 0) { red[w][0] = v0; red[w][1] = v1; red[w][2] = v2; }
  __syncthreads();
  if (tid == 0) {
    atomicAdd(&Asum[b * 3 + 0], red[0][0] + red[1][0] + red[2][0] + red[3][0]);
    atomicAdd(&Asum[b * 3 + 1], red[0][1] + red[1][1] + red[2][1] + red[3][1]);
    atomicAdd(&Asum[b * 3 + 2], red[0][2] + red[1][2] + red[2][2] + red[3][2]);
    __threadfence();
    unsigned tk = atomicAdd(doneCnt, 1u);
    lastA = (tk == 511);
  }
  __syncthreads();
  if (lastA && tid < 24)
    out[3 * HWn * 8 + tid] = atomicAdd(&Asum[tid], 0.f) * (1.0f / (float)KTOP);
}

extern "C" void kernel_launch(void* const* d_in, const int* in_sizes, int n_in,
                              void* d_out, int out_size, void* d_ws, size_t ws_size,
                              hipStream_t stream)
{
  const float* x     = (const float*)d_in[0];
  const float* w1    = (const float*)d_in[1];
  const float* b1    = (const float*)d_in[2];
  const float* w2    = (const float*)d_in[3];
  const float* b2    = (const float*)d_in[4];
  const float* cw    = (const float*)d_in[5];
  const float* cb    = (const float*)d_in[6];
  const float* convw = (const float*)d_in[7];
  const float* convb = (const float*)d_in[8];
  float* out = (float*)d_out;
  char* ws = (char*)d_ws;

  float*    bright    = (float*)(ws);                // 8 MB
  unsigned* h1        = (unsigned*)(ws + 8388608);   // 8192
  unsigned* h12       = (unsigned*)(ws + 8396800);   // 131072
  unsigned* h3        = (unsigned*)(ws + 8527872);   // 131072
  float*    Asum      = (float*)(ws + 8658944);      // 96
  unsigned* eqTaken   = (unsigned*)(ws + 8659040);   // 32
  float*    means     = (float*)(ws + 8659072);      // 96
  unsigned* meansDone = (unsigned*)(ws + 8659168);   // 32
  unsigned* accumDone = (unsigned*)(ws + 8659200);   // 32
  short*    w1Ag      = (short*)(ws + 8659232);      // 4096 B (16-aligned)
  short*    w2Ag      = (short*)(ws + 8663328);      // 18432 B
  float*    colorG    = (float*)(ws + 8681760);      // 96

  // zero h1, h12, h3, Asum, eqTaken, means, meansDone, accumDone
  hipMemsetAsync(ws + 8388608, 0, 8659232 - 8388608, stream);

  k_means<<<768, 256, 0, stream>>>(x, means, meansDone, w1, b1, w2, cw, cb, w1Ag, w2Ag, colorG);
  k_fused<<<dim3(32, 32, 8), 256, 0, stream>>>(x, b2, convw, convb, w1Ag, w2Ag, colorG, out);
  k_bright<<<dim3(128, 8), 256, 0, stream>>>(out, bright, h1);
  k_hist12<<<512, 256, 0, stream>>>(bright, h1, h12);
  k_hist3<<<512, 256, 0, stream>>>(bright, h1, h12, h3);
  k_accum<<<512, 256, 0, stream>>>(bright, out, h1, h12, h3, eqTaken, Asum, accumDone, out);
}